// Round 11
// baseline (25.488 us; speedup 1.0000x reference)
//
#include <hip/hip_runtime.h>
#include <math.h>

#ifndef M_PI
#define M_PI 3.14159265358979323846
#endif

#define MA 768   // MAX_ATOMS

// Full-wave (64-lane) sum via DPP on the VALU pipe; total lands in lane 63.
__device__ __forceinline__ float dpp_red_add(float v) {
    v += __int_as_float(__builtin_amdgcn_update_dpp(0, __float_as_int(v), 0x111, 0xf, 0xf, true)); // row_shr:1
    v += __int_as_float(__builtin_amdgcn_update_dpp(0, __float_as_int(v), 0x112, 0xf, 0xf, true)); // row_shr:2
    v += __int_as_float(__builtin_amdgcn_update_dpp(0, __float_as_int(v), 0x114, 0xf, 0xe, true)); // row_shr:4
    v += __int_as_float(__builtin_amdgcn_update_dpp(0, __float_as_int(v), 0x118, 0xf, 0xc, true)); // row_shr:8
    v += __int_as_float(__builtin_amdgcn_update_dpp(0, __float_as_int(v), 0x142, 0xa, 0xf, true)); // row_bcast:15
    v += __int_as_float(__builtin_amdgcn_update_dpp(0, __float_as_int(v), 0x143, 0xc, 0xf, true)); // row_bcast:31
    return v;
}

struct Sums {
    float sx0 = 0.f, sx1 = 0.f, sx2 = 0.f;
    float sy0 = 0.f, sy1 = 0.f, sy2 = 0.f;
    float c00 = 0.f, c01 = 0.f, c02 = 0.f;
    float c10 = 0.f, c11 = 0.f, c12 = 0.f;
    float c20 = 0.f, c21 = 0.f, c22 = 0.f;
    float nx2 = 0.f, ny2 = 0.f;
};

// Accumulate NA atoms per lane from registers, masking atoms >= n.
template<int NA>
__device__ __forceinline__ void accum(const float* ax, const float* ay,
                                      int a0, int n, Sums& S)
{
#pragma unroll
    for (int j = 0; j < NA; ++j) {
        const bool v = (a0 + j) < n;
        const float x0 = v ? ax[3 * j + 0] : 0.f;
        const float x1 = v ? ax[3 * j + 1] : 0.f;
        const float x2 = v ? ax[3 * j + 2] : 0.f;
        const float y0 = v ? ay[3 * j + 0] : 0.f;
        const float y1 = v ? ay[3 * j + 1] : 0.f;
        const float y2 = v ? ay[3 * j + 2] : 0.f;
        S.sx0 += x0; S.sx1 += x1; S.sx2 += x2;
        S.sy0 += y0; S.sy1 += y1; S.sy2 += y2;
        S.c00 = fmaf(x0, y0, S.c00); S.c01 = fmaf(x0, y1, S.c01); S.c02 = fmaf(x0, y2, S.c02);
        S.c10 = fmaf(x1, y0, S.c10); S.c11 = fmaf(x1, y1, S.c11); S.c12 = fmaf(x1, y2, S.c12);
        S.c20 = fmaf(x2, y0, S.c20); S.c21 = fmaf(x2, y1, S.c21); S.c22 = fmaf(x2, y2, S.c22);
        S.nx2 = fmaf(x0, x0, S.nx2); S.nx2 = fmaf(x1, x1, S.nx2); S.nx2 = fmaf(x2, x2, S.nx2);
        S.ny2 = fmaf(y0, y0, S.ny2); S.ny2 = fmaf(y1, y1, S.ny2); S.ny2 = fmaf(y2, y2, S.ny2);
    }
}

// ONE SAMPLE PER 128-THREAD BLOCK (2 waves). Wave 0: atoms [0,512), 8/lane,
// 12 dwordx4. Wave 1: atoms [512,768), 4/lane, 6 dwordx4 (skipped entirely
// when n <= 512). 16384 waves total -> >=2 occupancy rounds (backfill).
// DPP-reduce per wave; wave 1 passes 17 floats via LDS; wave 0 lane 63 runs
// the f32 eigensolve and writes out.
__global__ __launch_bounds__(128, 4) void kabsch_kernel(
    const float* __restrict__ inp, const float* __restrict__ tgt,
    const int* __restrict__ natoms, float* __restrict__ out)
{
    const int wave = threadIdx.x >> 6;
    const int lane = threadIdx.x & 63;
    const int b = blockIdx.x;
    const int n = natoms[b];
    const float* __restrict__ X = inp + (size_t)b * (3 * MA);
    const float* __restrict__ Y = tgt + (size_t)b * (3 * MA);

    __shared__ float part[17];

    Sums S;

    if (wave == 0) {
        const int a0 = 8 * lane;                 // atoms [0,512)
        float4 vx[6], vy[6];
        const float4 f4z = make_float4(0.f, 0.f, 0.f, 0.f);
#pragma unroll
        for (int k = 0; k < 6; ++k) { vx[k] = f4z; vy[k] = f4z; }
        if (a0 < n) {                            // lanes 0..47 always active
            const float4* px = (const float4*)(X + 24 * lane);
            const float4* py = (const float4*)(Y + 24 * lane);
#pragma unroll
            for (int k = 0; k < 6; ++k) vx[k] = px[k];
#pragma unroll
            for (int k = 0; k < 6; ++k) vy[k] = py[k];
        }
        __builtin_amdgcn_sched_barrier(0);

        float ax[24], ay[24];
#pragma unroll
        for (int k = 0; k < 6; ++k) {
            *(float4*)&ax[4 * k] = vx[k];
            *(float4*)&ay[4 * k] = vy[k];
        }
        accum<8>(ax, ay, a0, n, S);
    } else {
        const int a1 = 512 + 4 * lane;           // atoms [512,768)
        float4 vx[3], vy[3];
        const float4 f4z = make_float4(0.f, 0.f, 0.f, 0.f);
#pragma unroll
        for (int k = 0; k < 3; ++k) { vx[k] = f4z; vy[k] = f4z; }
        if (a1 < n) {                            // whole wave skips if n <= 512
            const float4* px = (const float4*)(X + 1536 + 12 * lane);
            const float4* py = (const float4*)(Y + 1536 + 12 * lane);
#pragma unroll
            for (int k = 0; k < 3; ++k) vx[k] = px[k];
#pragma unroll
            for (int k = 0; k < 3; ++k) vy[k] = py[k];
        }
        __builtin_amdgcn_sched_barrier(0);

        float ax[12], ay[12];
#pragma unroll
        for (int k = 0; k < 3; ++k) {
            *(float4*)&ax[4 * k] = vx[k];
            *(float4*)&ay[4 * k] = vy[k];
        }
        accum<4>(ax, ay, a1, n, S);
    }

    S.sx0 = dpp_red_add(S.sx0); S.sx1 = dpp_red_add(S.sx1); S.sx2 = dpp_red_add(S.sx2);
    S.sy0 = dpp_red_add(S.sy0); S.sy1 = dpp_red_add(S.sy1); S.sy2 = dpp_red_add(S.sy2);
    S.c00 = dpp_red_add(S.c00); S.c01 = dpp_red_add(S.c01); S.c02 = dpp_red_add(S.c02);
    S.c10 = dpp_red_add(S.c10); S.c11 = dpp_red_add(S.c11); S.c12 = dpp_red_add(S.c12);
    S.c20 = dpp_red_add(S.c20); S.c21 = dpp_red_add(S.c21); S.c22 = dpp_red_add(S.c22);
    S.nx2 = dpp_red_add(S.nx2); S.ny2 = dpp_red_add(S.ny2);

    if (wave == 1 && lane == 63) {
        part[ 0] = S.sx0; part[ 1] = S.sx1; part[ 2] = S.sx2;
        part[ 3] = S.sy0; part[ 4] = S.sy1; part[ 5] = S.sy2;
        part[ 6] = S.c00; part[ 7] = S.c01; part[ 8] = S.c02;
        part[ 9] = S.c10; part[10] = S.c11; part[11] = S.c12;
        part[12] = S.c20; part[13] = S.c21; part[14] = S.c22;
        part[15] = S.nx2; part[16] = S.ny2;
    }
    __syncthreads();

    // Fused epilogue on wave 0 lane 63 — ALL F32 (threshold 5e-2, err ~1e-4).
    if (wave == 0 && lane == 63) {
        const float sx0 = S.sx0 + part[ 0], sx1 = S.sx1 + part[ 1], sx2 = S.sx2 + part[ 2];
        const float sy0 = S.sy0 + part[ 3], sy1 = S.sy1 + part[ 4], sy2 = S.sy2 + part[ 5];
        const float c00 = S.c00 + part[ 6], c01 = S.c01 + part[ 7], c02 = S.c02 + part[ 8];
        const float c10 = S.c10 + part[ 9], c11 = S.c11 + part[10], c12 = S.c12 + part[11];
        const float c20 = S.c20 + part[12], c21 = S.c21 + part[13], c22 = S.c22 + part[14];
        const float nx2 = S.nx2 + part[15], ny2 = S.ny2 + part[16];

        const float inv_n = 1.0f / (float)n;

        const float R00 = fmaf(-sx0 * inv_n, sy0, c00);
        const float R01 = fmaf(-sx0 * inv_n, sy1, c01);
        const float R02 = fmaf(-sx0 * inv_n, sy2, c02);
        const float R10 = fmaf(-sx1 * inv_n, sy0, c10);
        const float R11 = fmaf(-sx1 * inv_n, sy1, c11);
        const float R12 = fmaf(-sx1 * inv_n, sy2, c12);
        const float R20 = fmaf(-sx2 * inv_n, sy0, c20);
        const float R21 = fmaf(-sx2 * inv_n, sy1, c21);
        const float R22 = fmaf(-sx2 * inv_n, sy2, c22);
        const float ex = nx2 - (sx0 * sx0 + sx1 * sx1 + sx2 * sx2) * inv_n;
        const float ey = ny2 - (sy0 * sy0 + sy1 * sy1 + sy2 * sy2) * inv_n;

        const float A00 = R00 * R00 + R10 * R10 + R20 * R20;
        const float A11 = R01 * R01 + R11 * R11 + R21 * R21;
        const float A22 = R02 * R02 + R12 * R12 + R22 * R22;
        const float A01 = R00 * R01 + R10 * R11 + R20 * R21;
        const float A02 = R00 * R02 + R10 * R12 + R20 * R22;
        const float A12 = R01 * R02 + R11 * R12 + R21 * R22;

        const float detR = R00 * (R11 * R22 - R12 * R21)
                         - R01 * (R10 * R22 - R12 * R20)
                         + R02 * (R10 * R21 - R11 * R20);

        const float q = (A00 + A11 + A22) * (1.0f / 3.0f);
        const float p1 = A01 * A01 + A02 * A02 + A12 * A12;
        const float b00 = A00 - q, b11 = A11 - q, b22 = A22 - q;
        const float p2 = b00 * b00 + b11 * b11 + b22 * b22 + 2.0f * p1;
        float e0, e1, e2;
        if (p2 <= 0.0f) {
            e0 = e1 = e2 = q;
        } else {
            const float p = sqrtf(p2 * (1.0f / 6.0f));
            const float ip = 1.0f / p;
            const float B00 = b00 * ip, B11 = b11 * ip, B22 = b22 * ip;
            const float B01 = A01 * ip, B02 = A02 * ip, B12 = A12 * ip;
            const float detB = B00 * (B11 * B22 - B12 * B12)
                             - B01 * (B01 * B22 - B12 * B02)
                             + B02 * (B01 * B12 - B11 * B02);
            float rr = 0.5f * detB;
            rr = fminf(1.0f, fmaxf(-1.0f, rr));
            const float phi = acosf(rr) * (1.0f / 3.0f);
            const float cA = __cosf(phi);
            const float cC = __cosf(phi + (float)(2.0 * M_PI / 3.0));
            e0 = fmaf(2.0f * p, cA, q);
            e2 = fmaf(2.0f * p, cC, q);
            e1 = 3.0f * q - e0 - e2;
        }
        const float s0 = sqrtf(fmaxf(e0, 0.0f));
        const float s1 = sqrtf(fmaxf(e1, 0.0f));
        const float s2 = sqrtf(fmaxf(e2, 0.0f));
        const float d = (detR > 0.0f) ? 1.0f : ((detR < 0.0f) ? -1.0f : 0.0f);
        const float tr = s0 + s1 + d * s2;
        const float e = ex + ey - 2.0f * tr;
        out[b] = sqrtf(fmaxf(e, 0.0f) * inv_n + 1e-7f);
    }
}

extern "C" void kernel_launch(void* const* d_in, const int* in_sizes, int n_in,
                              void* d_out, int out_size, void* d_ws, size_t ws_size,
                              hipStream_t stream) {
    const float* inp = (const float*)d_in[0];
    const float* tgt = (const float*)d_in[1];
    const int* natoms = (const int*)d_in[2];
    float* out = (float*)d_out;
    (void)d_ws; (void)ws_size; (void)n_in; (void)in_sizes;
    kabsch_kernel<<<dim3(out_size), dim3(128), 0, stream>>>(inp, tgt, natoms, out);
}